// Round 12
// baseline (23679.305 us; speedup 1.0000x reference)
//
#include <hip/hip_runtime.h>
#include <hip/hip_bf16.h>
#include <hip/hip_fp16.h>

// Problem constants
#define B_ 64
#define T_ 512
#define D_ 256
#define H_ 512
#define M_ (B_*T_)          // 32768

#define NBLK 64             // scan blocks
#define JO 8                // hidden columns owned per scan block

typedef unsigned int uint;
typedef unsigned long long u64;
typedef __attribute__((ext_vector_type(8))) short bf16x8;
typedef __attribute__((ext_vector_type(4))) float f32x4;
typedef _Float16 half_t;
typedef __attribute__((ext_vector_type(2))) _Float16 half2_t;

__device__ __forceinline__ unsigned short f32_to_bf16(float f) {
    unsigned u = __builtin_bit_cast(unsigned, f);
    unsigned r = (u + 0x7fffu + ((u >> 16) & 1u)) >> 16;
    return (unsigned short)r;
}
__device__ __forceinline__ float bf16_to_f32(unsigned short h) {
    unsigned u = ((unsigned)h) << 16;
    return __builtin_bit_cast(float, u);
}
__device__ __forceinline__ unsigned pkh2(float a, float b) {
    half2_t h; h.x = (half_t)a; h.y = (half_t)b;
    return __builtin_bit_cast(unsigned, h);
}
__device__ __forceinline__ half2_t uph2(unsigned u) {
    return __builtin_bit_cast(half2_t, u);
}

#if __has_builtin(__builtin_amdgcn_fdot2)
__device__ __forceinline__ float fdot2(half2_t a, half2_t b, float c) {
    return __builtin_amdgcn_fdot2(a, b, c, false);
}
#else
__device__ __forceinline__ float fdot2(half2_t a, half2_t b, float c) {
    return c + (float)a.x * (float)b.x + (float)a.y * (float)b.y;
}
#endif

// agent-scope (cross-XCD coherent, L2-bypassing) relaxed 64-bit atomics.
// Each exchange element is a self-tagged 8B word {payload(lo32), tag(hi32)}:
// tag and payload travel in ONE single-copy-atomic word, so consumers that
// observe the tag necessarily observe the matching payload. No flags, no
// drains, no ordering edges needed.
__device__ __forceinline__ u64 ald64(const u64* p) {
    return __hip_atomic_load(p, __ATOMIC_RELAXED, __HIP_MEMORY_SCOPE_AGENT);
}
__device__ __forceinline__ void ast64(u64* p, u64 v) {
    __hip_atomic_store(p, v, __ATOMIC_RELAXED, __HIP_MEMORY_SCOPE_AGENT);
}
__device__ __forceinline__ u64 pack_tag(uint data, uint tag) {
    return ((u64)tag << 32) | (u64)data;
}

__device__ __forceinline__ float sigmoidf_(float x) {
    return 1.f / (1.f + __expf(-x));
}

// ---------------------------------------------------------------------------
// P = We2h @ W  for r and z gates
// ---------------------------------------------------------------------------
__global__ void comp_p(const float* __restrict__ We2h, const float* __restrict__ Wre,
                       const float* __restrict__ Wze,
                       float* __restrict__ Pr, float* __restrict__ Pz) {
    int tid = blockIdx.x * blockDim.x + threadIdx.x;   // 256*512
    if (tid >= 256 * 512) return;
    int k = tid >> 9, j = tid & 511;
    float ar = 0.f, az = 0.f;
    for (int kk = 0; kk < 512; kk++) {
        float e = We2h[k * 512 + kk];
        ar += e * Wre[kk * 512 + j];
        az += e * Wze[kk * 512 + j];
    }
    Pr[tid] = ar;
    Pz[tid] = az;
}

// ---------------------------------------------------------------------------
// Build bf16 weights for the big GEMMs.
// ---------------------------------------------------------------------------
__global__ void build_wt(const float* __restrict__ We2h, const float* __restrict__ Wrx,
                         const float* __restrict__ Wzx, const float* __restrict__ Wnx,
                         const float* __restrict__ Pr, const float* __restrict__ Pz,
                         const float* __restrict__ br, const float* __restrict__ bz,
                         const float* __restrict__ bn, const float* __restrict__ Wo,
                         unsigned short* __restrict__ WcatT, float* __restrict__ biascat,
                         unsigned short* __restrict__ WoT) {
    int tid = blockIdx.x * blockDim.x + threadIdx.x;
    const int total1 = 2048 * 256;
    if (tid < total1) {
        int n = tid >> 8, k = tid & 255;
        int sel = n >> 9, nl = n & 511;
        float v;
        if (sel == 0)      v = We2h[k * 512 + nl];
        else if (sel == 1) v = Wrx[k * 512 + nl] + Pr[k * 512 + nl];
        else if (sel == 2) v = Wzx[k * 512 + nl] + Pz[k * 512 + nl];
        else               v = Wnx[k * 512 + nl];
        WcatT[tid] = f32_to_bf16(v);
        if (k == 0) {
            float bv = sel == 0 ? 0.f : sel == 1 ? br[nl] : sel == 2 ? bz[nl] : bn[nl];
            biascat[n] = bv;
        }
    } else {
        int t2 = tid - total1;
        if (t2 < 256 * 512) {
            int n = t2 >> 9, k = t2 & 511;
            WoT[t2] = f32_to_bf16(Wo[k * 256 + n]);
        }
    }
}

// ---------------------------------------------------------------------------
// Packed f16 recurrent weights (transformed):
//  warz uint2 [256 kp][512 j]: {pkh2(Ar[2kp],Ar[2kp+1]), pkh2(Az...)}, A=Wh-We
//  wan  uint  [512 k][512 j]:  pkh2(An[k][j], Wne[k][j]),  An = Wnh - Wne
// ---------------------------------------------------------------------------
__global__ void build_wscan(const float* __restrict__ Wrh, const float* __restrict__ Wre,
                            const float* __restrict__ Wzh, const float* __restrict__ Wze,
                            const float* __restrict__ Wnh, const float* __restrict__ Wne,
                            uint2* __restrict__ warz, uint* __restrict__ wan) {
    int tid = blockIdx.x * blockDim.x + threadIdx.x;
    if (tid < 256 * 512) {
        int kp = tid >> 9, j = tid & 511;
        int k0 = 2 * kp;
        float ar0 = Wrh[k0 * 512 + j] - Wre[k0 * 512 + j];
        float ar1 = Wrh[(k0 + 1) * 512 + j] - Wre[(k0 + 1) * 512 + j];
        float az0 = Wzh[k0 * 512 + j] - Wze[k0 * 512 + j];
        float az1 = Wzh[(k0 + 1) * 512 + j] - Wze[(k0 + 1) * 512 + j];
        warz[tid] = make_uint2(pkh2(ar0, ar1), pkh2(az0, az1));
    }
    int t2 = tid - 256 * 512;
    if (t2 >= 0 && t2 < 512 * 512) {
        int k = t2 >> 9, j = t2 & 511;
        float an = Wnh[k * 512 + j] - Wne[k * 512 + j];
        wan[t2] = pkh2(an, Wne[k * 512 + j]);
    }
}

// ---------------------------------------------------------------------------
// init hbuf2: [256 kp][64 m] u64 = {pkh2(h[m][2kp], h[m][2kp+1]), tag=0}
// ---------------------------------------------------------------------------
__global__ void init_hbuf(const float* __restrict__ h0, u64* __restrict__ hbuf2) {
    int tid = blockIdx.x * blockDim.x + threadIdx.x;   // 256*64
    if (tid >= 256 * 64) return;
    int kp = tid >> 6, m = tid & 63;
    hbuf2[tid] = pack_tag(pkh2(h0[m * 512 + 2 * kp], h0[m * 512 + 2 * kp + 1]), 0u);
}

// ---------------------------------------------------------------------------
// GEMM-X: writes xproj directly in scan layout xT[t][col][m] bf16.
// ---------------------------------------------------------------------------
__global__ __launch_bounds__(256)
void gemmx_kernel(const float* __restrict__ A, const unsigned short* __restrict__ BT,
                  const float* __restrict__ bias, unsigned short* __restrict__ xT) {
    __shared__ unsigned short Asm[128 * 64];
    __shared__ unsigned short Bsm[128 * 64];
    __shared__ unsigned short Csm[128][128];   // [col][row]
    const int tid = threadIdx.x;
    const int t0 = blockIdx.x * 2;        // time-pair
    const int c0 = blockIdx.y * 128;      // col tile
    const int lane = tid & 63, wid = tid >> 6;
    const int wm = wid >> 1, wn = wid & 1;
    const int lr = lane & 15, lg = lane >> 4;

    f32x4 acc[4][4] = {};

    const int srow = tid >> 1, shalf = tid & 1;
    const int rowA = (srow & 63) * 512 + t0 + (srow >> 6);     // (b,t) -> A row
    const float* Arow = A + (size_t)rowA * 256 + shalf * 32;
    const unsigned short* Brow = BT + (size_t)(c0 + srow) * 256 + shalf * 32;
    unsigned short* As = &Asm[srow * 64 + shalf * 32];
    unsigned short* Bs = &Bsm[srow * 64 + shalf * 32];

    for (int kt = 0; kt < 256; kt += 64) {
#pragma unroll
        for (int q = 0; q < 8; q++) {
            float4 v = *(const float4*)(Arow + kt + q * 4);
            unsigned p0 = ((unsigned)f32_to_bf16(v.y) << 16) | f32_to_bf16(v.x);
            unsigned p1 = ((unsigned)f32_to_bf16(v.w) << 16) | f32_to_bf16(v.z);
            *(uint2*)(As + q * 4) = make_uint2(p0, p1);
        }
#pragma unroll
        for (int q = 0; q < 4; q++) {
            uint4 v = *(const uint4*)(Brow + kt + q * 8);
            *(uint4*)(Bs + q * 8) = v;
        }
        __syncthreads();
#pragma unroll
        for (int ks = 0; ks < 2; ks++) {
            bf16x8 af[4], bfr[4];
#pragma unroll
            for (int m = 0; m < 4; m++)
                af[m] = *(const bf16x8*)&Asm[(wm * 64 + m * 16 + lr) * 64 + ks * 32 + lg * 8];
#pragma unroll
            for (int n2 = 0; n2 < 4; n2++)
                bfr[n2] = *(const bf16x8*)&Bsm[(wn * 64 + n2 * 16 + lr) * 64 + ks * 32 + lg * 8];
#pragma unroll
            for (int m = 0; m < 4; m++)
#pragma unroll
                for (int n2 = 0; n2 < 4; n2++)
                    acc[m][n2] = __builtin_amdgcn_mfma_f32_16x16x32_bf16(
                        af[m], bfr[n2], acc[m][n2], 0, 0, 0);
        }
        __syncthreads();
    }
#pragma unroll
    for (int m = 0; m < 4; m++) {
        int r0 = wm * 64 + m * 16 + lg * 4;
#pragma unroll
        for (int n2 = 0; n2 < 4; n2++) {
            int c = wn * 64 + n2 * 16 + lr;
            float bv = bias[c0 + c];
#pragma unroll
            for (int i = 0; i < 4; i++)
                Csm[c][r0 + i] = f32_to_bf16(acc[m][n2][i] + bv);
        }
    }
    __syncthreads();
#pragma unroll
    for (int th = 0; th < 2; th++) {
        uint4* dst = (uint4*)(xT + ((size_t)(t0 + th) * 2048 + c0) * 64);
        for (int q = tid; q < 1024; q += 256) {
            int c = q >> 3, b0 = (q & 7) * 8;
            dst[q] = *(const uint4*)&Csm[c][th * 64 + b0];
        }
        __syncthreads();
    }
}

// ---------------------------------------------------------------------------
// Readout GEMM: A fp32 [M][K], BT bf16 [N][K], C fp32 + bias.
// ---------------------------------------------------------------------------
__global__ __launch_bounds__(256)
void gemm_out_kernel(const float* __restrict__ A, const unsigned short* __restrict__ BT,
                     const float* __restrict__ bias, float* __restrict__ C,
                     int M, int N, int K) {
    __shared__ unsigned short Asm[128 * 64];
    __shared__ unsigned short Bsm[128 * 64];
    const int tid = threadIdx.x;
    const int bm = blockIdx.x, bn = blockIdx.y;
    const int lane = tid & 63, wid = tid >> 6;
    const int wm = wid >> 1, wn = wid & 1;
    const int lr = lane & 15, lg = lane >> 4;

    f32x4 acc[4][4] = {};

    const int srow = tid >> 1, shalf = tid & 1;
    const float* Arow = A + (size_t)(bm * 128 + srow) * K + shalf * 32;
    const unsigned short* Brow = BT + (size_t)(bn * 128 + srow) * K + shalf * 32;
    unsigned short* As = &Asm[srow * 64 + shalf * 32];
    unsigned short* Bs = &Bsm[srow * 64 + shalf * 32];

    for (int kt = 0; kt < K; kt += 64) {
#pragma unroll
        for (int q = 0; q < 8; q++) {
            float4 v = *(const float4*)(Arow + kt + q * 4);
            unsigned p0 = ((unsigned)f32_to_bf16(v.y) << 16) | f32_to_bf16(v.x);
            unsigned p1 = ((unsigned)f32_to_bf16(v.w) << 16) | f32_to_bf16(v.z);
            *(uint2*)(As + q * 4) = make_uint2(p0, p1);
        }
#pragma unroll
        for (int q = 0; q < 4; q++) {
            uint4 v = *(const uint4*)(Brow + kt + q * 8);
            *(uint4*)(Bs + q * 8) = v;
        }
        __syncthreads();
#pragma unroll
        for (int ks = 0; ks < 2; ks++) {
            bf16x8 af[4], bfr[4];
#pragma unroll
            for (int m = 0; m < 4; m++)
                af[m] = *(const bf16x8*)&Asm[(wm * 64 + m * 16 + lr) * 64 + ks * 32 + lg * 8];
#pragma unroll
            for (int n2 = 0; n2 < 4; n2++)
                bfr[n2] = *(const bf16x8*)&Bsm[(wn * 64 + n2 * 16 + lr) * 64 + ks * 32 + lg * 8];
#pragma unroll
            for (int m = 0; m < 4; m++)
#pragma unroll
                for (int n2 = 0; n2 < 4; n2++)
                    acc[m][n2] = __builtin_amdgcn_mfma_f32_16x16x32_bf16(
                        af[m], bfr[n2], acc[m][n2], 0, 0, 0);
        }
        __syncthreads();
    }
#pragma unroll
    for (int m = 0; m < 4; m++) {
        int row0 = bm * 128 + wm * 64 + m * 16 + lg * 4;
#pragma unroll
        for (int n2 = 0; n2 < 4; n2++) {
            int col = bn * 128 + wn * 64 + n2 * 16 + lr;
            float bv = bias[col];
#pragma unroll
            for (int i = 0; i < 4; i++)
                C[(size_t)(row0 + i) * N + col] = acc[m][n2][i] + bv;
        }
    }
}

// ---------------------------------------------------------------------------
// Grid-synced weight-stationary scan with SELF-TAGGED exchange data.
// 64 blocks x 512 threads; block owns j = bid*8..+8 for all 64 batches.
// hbuf2[kp][m] / rhrxe2[k][m] are u64 {f16-pair, step-tag}. Consumers poll
// the data elements directly until tag matches (exact): tag and payload are
// one single-copy-atomic word -> race-free by construction, no flags, no
// producer drains. Retry loops are fully unrolled (static indices, rule #20)
// and reload only stale elements; spins bounded (fail loud, not hang).
// WAR safety: a block writes tag-(t+2) hbuf only after observing tag-(t+2)
// rhrxe from all producers, which requires their phase A(t+1), which read
// ALL tag-(t+1) hbuf -> nobody still needs tag-(t+1). Symmetric for rhrxe.
// Tags: hbuf expects ==t (init writes 0), rhrxe expects ==t+1 (memset to 0
// each launch, so stale cross-call tags never match).
// ---------------------------------------------------------------------------
__global__ __launch_bounds__(512)
void scan_sync(const unsigned short* __restrict__ xT,   // [512 t][2048 col][64 m] bf16
               const float* __restrict__ h0,            // [64 m][512 j]
               const uint2* __restrict__ warz,          // [256 kp][512 j]
               const uint* __restrict__ wan,            // [512 k][512 j]
               u64* __restrict__ hbuf2,                 // [256 kp][64 m] tagged
               u64* __restrict__ rhrxe2,                // [512 k][64 m] tagged
               float* __restrict__ hseq)                // [64 m][512 t][512 j]
{
    __shared__ uint2 Wrz_l[256][JO];                    // 16 KB
    __shared__ uint  Wn_l[512][JO];                     // 16 KB
    __shared__ float part[3][8][JO][64];                // 48 KB
    __shared__ float h_loc[JO][64], z_loc[JO][64];      // 4 KB

    const int bid = blockIdx.x, tid = threadIdx.x;
    const int lane = tid & 63, wv = tid >> 6;           // 8 waves
    const int j0 = bid * JO;
    const int jF = tid >> 6, mF = tid & 63;             // finalize mapping

    // one-time: weights -> LDS, local h slice
    for (int i = tid; i < 256 * JO; i += 512) {
        int kp = i >> 3, j = i & 7;
        Wrz_l[kp][j] = warz[kp * 512 + j0 + j];
    }
    for (int i = tid; i < 512 * JO; i += 512) {
        int k = i >> 3, j = i & 7;
        Wn_l[k][j] = wan[k * 512 + j0 + j];
    }
    h_loc[jF][mF] = h0[mF * 512 + j0 + jF];
    __syncthreads();

    const int jg = j0 + jF;
    const size_t xoff = (size_t)jg * 64 + mF;

    for (int t = 0; t < T_; t++) {
        const uint tagH = (uint)t;          // hbuf freshness for this step
        const uint tagR = (uint)t + 1u;     // rhrxe freshness for this step

        // xT gate loads: issued early, latency hides under the hbuf poll
        const size_t xb = (size_t)t * 2048 * 64 + xoff;
        unsigned short pxe = xT[xb];
        unsigned short pxr = xT[xb + (size_t)512 * 64];
        unsigned short pxz = xT[xb + (size_t)1024 * 64];
        unsigned short pxn = xT[xb + (size_t)1536 * 64];

        // ---- phase A: poll-load hbuf rows (wave wv: kp = wv*32..+32) ----
        {
            u64 raw[32];
#pragma unroll
            for (int q = 0; q < 32; q++)
                raw[q] = ald64(&hbuf2[(wv * 32 + q) * 64 + lane]);
            int it = 0;
            while (true) {
                uint stale = 0;
#pragma unroll
                for (int q = 0; q < 32; q++)
                    stale |= ((uint)(raw[q] >> 32) != tagH) ? 1u : 0u;
                if (!__any(stale) || ++it > (1 << 22)) break;
#pragma unroll
                for (int q = 0; q < 32; q++)
                    if ((uint)(raw[q] >> 32) != tagH)
                        raw[q] = ald64(&hbuf2[(wv * 32 + q) * 64 + lane]);
            }
            float ar[JO] = {}, az[JO] = {};
#pragma unroll
            for (int q = 0; q < 32; q++) {
                half2_t h2 = uph2((uint)raw[q]);
#pragma unroll
                for (int j = 0; j < JO; j++) {
                    uint2 w = *(const uint2*)&Wrz_l[wv * 32 + q][j];
                    ar[j] = fdot2(h2, uph2(w.x), ar[j]);
                    az[j] = fdot2(h2, uph2(w.y), az[j]);
                }
            }
#pragma unroll
            for (int j = 0; j < JO; j++) {
                part[0][wv][j][lane] = ar[j];
                part[1][wv][j][lane] = az[j];
            }
        }
        __syncthreads();

        // ---- finalize A: sigmoid, publish tagged (r*h, r*xe) ----
        float xn_f = bf16_to_f32(pxn);
        {
            float sr = 0.f, sz = 0.f;
#pragma unroll
            for (int w = 0; w < 8; w++) { sr += part[0][w][jF][mF]; sz += part[1][w][jF][mF]; }
            float r = sigmoidf_(bf16_to_f32(pxr) + sr);
            float z = sigmoidf_(bf16_to_f32(pxz) + sz);
            float h = h_loc[jF][mF];
            z_loc[jF][mF] = z;
            ast64(&rhrxe2[jg * 64 + mF],
                  pack_tag(pkh2(r * h, r * bf16_to_f32(pxe)), tagR));
        }
        // no barrier, no drain: each rhrxe element is self-tagged

        // ---- phase B: poll-load rhrxe rows (wave wv: k = wv*64..+64) ----
        {
            float an[JO] = {};
#pragma unroll
            for (int ch = 0; ch < 2; ch++) {
                u64 raw[32];
#pragma unroll
                for (int q = 0; q < 32; q++)
                    raw[q] = ald64(&rhrxe2[(wv * 64 + ch * 32 + q) * 64 + lane]);
                int it = 0;
                while (true) {
                    uint stale = 0;
#pragma unroll
                    for (int q = 0; q < 32; q++)
                        stale |= ((uint)(raw[q] >> 32) != tagR) ? 1u : 0u;
                    if (!__any(stale) || ++it > (1 << 22)) break;
#pragma unroll
                    for (int q = 0; q < 32; q++)
                        if ((uint)(raw[q] >> 32) != tagR)
                            raw[q] = ald64(&rhrxe2[(wv * 64 + ch * 32 + q) * 64 + lane]);
                }
#pragma unroll
                for (int q = 0; q < 32; q++) {
                    half2_t p2 = uph2((uint)raw[q]);
#pragma unroll
                    for (int j = 0; j < JO; j++)
                        an[j] = fdot2(p2, uph2(Wn_l[wv * 64 + ch * 32 + q][j]), an[j]);
                }
            }
#pragma unroll
            for (int j = 0; j < JO; j++) part[2][wv][j][lane] = an[j];
        }
        __syncthreads();

        // ---- finalize B: tanh, h update ----
        {
            float sn = 0.f;
#pragma unroll
            for (int w = 0; w < 8; w++) sn += part[2][w][jF][mF];
            float nn = tanhf(xn_f + sn);
            float z = z_loc[jF][mF];
            float h = h_loc[jF][mF];
            h_loc[jF][mF] = (1.f - z) * h + z * nn;
        }
        __syncthreads();

        // ---- publish new h (tagged f16 pairs) ----
        if (tid < (JO / 2) * 64) {
            int jp = tid >> 6, mh = tid & 63;
            ast64(&hbuf2[(bid * (JO / 2) + jp) * 64 + mh],
                  pack_tag(pkh2(h_loc[2 * jp][mh], h_loc[2 * jp + 1][mh]),
                           (uint)t + 1u));
        }
        // ---- hseq write: off the critical path ----
        {
            int js = tid & 7, ms = tid >> 3;
            hseq[((size_t)ms * 512 + t) * 512 + j0 + js] = h_loc[js][ms];
        }
    }
}

// ---------------------------------------------------------------------------
extern "C" void kernel_launch(void* const* d_in, const int* in_sizes, int n_in,
                              void* d_out, int out_size, void* d_ws, size_t ws_size,
                              hipStream_t stream) {
    const float* x    = (const float*)d_in[0];
    const float* h0   = (const float*)d_in[1];
    const float* We2h = (const float*)d_in[2];
    const float* Wrx  = (const float*)d_in[3];
    const float* Wrh  = (const float*)d_in[4];
    const float* Wre  = (const float*)d_in[5];
    const float* br   = (const float*)d_in[6];
    const float* Wzx  = (const float*)d_in[7];
    const float* Wzh  = (const float*)d_in[8];
    const float* Wze  = (const float*)d_in[9];
    const float* bz   = (const float*)d_in[10];
    const float* Wnx  = (const float*)d_in[11];
    const float* Wnh  = (const float*)d_in[12];
    const float* Wne  = (const float*)d_in[13];
    const float* bn   = (const float*)d_in[14];
    const float* Wo   = (const float*)d_in[15];
    const float* bo   = (const float*)d_in[16];

    // workspace layout (bytes)
    char* w = (char*)d_ws;
    unsigned short* xT    = (unsigned short*)(w);                  // 134217728
    uint2*          warz  = (uint2*)(w + 134217728);               // 1048576
    uint*           wan   = (uint*)(w + 135266304);                // 1048576
    unsigned short* WcatT = (unsigned short*)(w + 136314880);      // 1048576
    unsigned short* WoT   = (unsigned short*)(w + 137363456);      // 262144
    float*          biascat = (float*)(w + 137625600);             // 8192
    float*          Pr    = (float*)(w + 137633792);               // 524288
    float*          Pz    = (float*)(w + 138158080);               // 524288
    u64*            hbuf2 = (u64*)(w + 138682368);                 // 131072
    u64*            rhrxe2= (u64*)(w + 138813440);                 // 262144

    float* out  = (float*)d_out;                    // [B,T,D]
    float* hseq = (float*)d_out + (size_t)M_ * D_;  // [B,T,H]

    // zero rhrxe tags each launch (cross-call: stale tags must never match)
    hipMemsetAsync(rhrxe2, 0, 262144, stream);

    // 1. composite input weights + packed scan weights
    comp_p<<<(256 * 512 + 255) / 256, 256, 0, stream>>>(We2h, Wre, Wze, Pr, Pz);
    build_wt<<<(2048 * 256 + 256 * 512 + 255) / 256, 256, 0, stream>>>(
        We2h, Wrx, Wzx, Wnx, Pr, Pz, br, bz, bn, Wo, WcatT, biascat, WoT);
    build_wscan<<<(256 * 512 + 512 * 512 + 255) / 256, 256, 0, stream>>>(
        Wrh, Wre, Wzh, Wze, Wnh, Wne, warz, wan);
    init_hbuf<<<(256 * 64 + 255) / 256, 256, 0, stream>>>(h0, hbuf2);

    // 2. pre-projections directly into xT[t][col][m]
    {
        dim3 grid(T_ / 2, 2048 / 128);
        gemmx_kernel<<<grid, 256, 0, stream>>>(x, WcatT, biascat, xT);
    }
    // 3. scan with self-tagged exchanges -> hseq
    scan_sync<<<NBLK, 512, 0, stream>>>(xT, h0, warz, wan, hbuf2, rhrxe2, hseq);
    // 4. readout: [32768,512] @ [512,256] + bo -> out
    {
        dim3 grid(M_ / 128, D_ / 128);
        gemm_out_kernel<<<grid, 256, 0, stream>>>(hseq, WoT, bo, out, M_, D_, H_);
    }
}

// Round 13
// 23474.982 us; speedup vs baseline: 1.0087x; 1.0087x over previous
//
#include <hip/hip_runtime.h>
#include <hip/hip_bf16.h>
#include <hip/hip_fp16.h>

// Problem constants
#define B_ 64
#define T_ 512
#define D_ 256
#define H_ 512
#define M_ (B_*T_)          // 32768

#define NBLK 64             // scan blocks
#define JO 8                // hidden columns owned per scan block

typedef unsigned int uint;
typedef unsigned long long u64;
typedef __attribute__((ext_vector_type(8))) short bf16x8;
typedef __attribute__((ext_vector_type(4))) float f32x4;
typedef _Float16 half_t;
typedef __attribute__((ext_vector_type(2))) _Float16 half2_t;

__device__ __forceinline__ unsigned short f32_to_bf16(float f) {
    unsigned u = __builtin_bit_cast(unsigned, f);
    unsigned r = (u + 0x7fffu + ((u >> 16) & 1u)) >> 16;
    return (unsigned short)r;
}
__device__ __forceinline__ float bf16_to_f32(unsigned short h) {
    unsigned u = ((unsigned)h) << 16;
    return __builtin_bit_cast(float, u);
}
__device__ __forceinline__ unsigned pkh2(float a, float b) {
    half2_t h; h.x = (half_t)a; h.y = (half_t)b;
    return __builtin_bit_cast(unsigned, h);
}
__device__ __forceinline__ half2_t uph2(unsigned u) {
    return __builtin_bit_cast(half2_t, u);
}

#if __has_builtin(__builtin_amdgcn_fdot2)
__device__ __forceinline__ float fdot2(half2_t a, half2_t b, float c) {
    return __builtin_amdgcn_fdot2(a, b, c, false);
}
#else
__device__ __forceinline__ float fdot2(half2_t a, half2_t b, float c) {
    return c + (float)a.x * (float)b.x + (float)a.y * (float)b.y;
}
#endif

// agent-scope (cross-XCD coherent) relaxed 64-bit atomics. Each exchange
// element is a self-tagged 8B word {payload(lo32), tag(hi32)}: tag and
// payload travel in ONE single-copy-atomic word, so observing the tag
// implies observing the matching payload. Race-free by construction.
__device__ __forceinline__ u64 ald64(const u64* p) {
    return __hip_atomic_load(p, __ATOMIC_RELAXED, __HIP_MEMORY_SCOPE_AGENT);
}
__device__ __forceinline__ void ast64(u64* p, u64 v) {
    __hip_atomic_store(p, v, __ATOMIC_RELAXED, __HIP_MEMORY_SCOPE_AGENT);
}
__device__ __forceinline__ u64 pack_tag(uint data, uint tag) {
    return ((u64)tag << 32) | (u64)data;
}

__device__ __forceinline__ float sigmoidf_(float x) {
    return 1.f / (1.f + __expf(-x));
}

// ---------------------------------------------------------------------------
// P = We2h @ W  for r and z gates
// ---------------------------------------------------------------------------
__global__ void comp_p(const float* __restrict__ We2h, const float* __restrict__ Wre,
                       const float* __restrict__ Wze,
                       float* __restrict__ Pr, float* __restrict__ Pz) {
    int tid = blockIdx.x * blockDim.x + threadIdx.x;   // 256*512
    if (tid >= 256 * 512) return;
    int k = tid >> 9, j = tid & 511;
    float ar = 0.f, az = 0.f;
    for (int kk = 0; kk < 512; kk++) {
        float e = We2h[k * 512 + kk];
        ar += e * Wre[kk * 512 + j];
        az += e * Wze[kk * 512 + j];
    }
    Pr[tid] = ar;
    Pz[tid] = az;
}

// ---------------------------------------------------------------------------
// Build bf16 weights for the big GEMMs.
// ---------------------------------------------------------------------------
__global__ void build_wt(const float* __restrict__ We2h, const float* __restrict__ Wrx,
                         const float* __restrict__ Wzx, const float* __restrict__ Wnx,
                         const float* __restrict__ Pr, const float* __restrict__ Pz,
                         const float* __restrict__ br, const float* __restrict__ bz,
                         const float* __restrict__ bn, const float* __restrict__ Wo,
                         unsigned short* __restrict__ WcatT, float* __restrict__ biascat,
                         unsigned short* __restrict__ WoT) {
    int tid = blockIdx.x * blockDim.x + threadIdx.x;
    const int total1 = 2048 * 256;
    if (tid < total1) {
        int n = tid >> 8, k = tid & 255;
        int sel = n >> 9, nl = n & 511;
        float v;
        if (sel == 0)      v = We2h[k * 512 + nl];
        else if (sel == 1) v = Wrx[k * 512 + nl] + Pr[k * 512 + nl];
        else if (sel == 2) v = Wzx[k * 512 + nl] + Pz[k * 512 + nl];
        else               v = Wnx[k * 512 + nl];
        WcatT[tid] = f32_to_bf16(v);
        if (k == 0) {
            float bv = sel == 0 ? 0.f : sel == 1 ? br[nl] : sel == 2 ? bz[nl] : bn[nl];
            biascat[n] = bv;
        }
    } else {
        int t2 = tid - total1;
        if (t2 < 256 * 512) {
            int n = t2 >> 9, k = t2 & 511;
            WoT[t2] = f32_to_bf16(Wo[k * 256 + n]);
        }
    }
}

// ---------------------------------------------------------------------------
// Packed f16 recurrent weights (transformed):
//  warz uint2 [256 kp][512 j]: {pkh2(Ar[2kp],Ar[2kp+1]), pkh2(Az...)}, A=Wh-We
//  wan  uint  [512 k][512 j]:  pkh2(An[k][j], Wne[k][j]),  An = Wnh - Wne
// ---------------------------------------------------------------------------
__global__ void build_wscan(const float* __restrict__ Wrh, const float* __restrict__ Wre,
                            const float* __restrict__ Wzh, const float* __restrict__ Wze,
                            const float* __restrict__ Wnh, const float* __restrict__ Wne,
                            uint2* __restrict__ warz, uint* __restrict__ wan) {
    int tid = blockIdx.x * blockDim.x + threadIdx.x;
    if (tid < 256 * 512) {
        int kp = tid >> 9, j = tid & 511;
        int k0 = 2 * kp;
        float ar0 = Wrh[k0 * 512 + j] - Wre[k0 * 512 + j];
        float ar1 = Wrh[(k0 + 1) * 512 + j] - Wre[(k0 + 1) * 512 + j];
        float az0 = Wzh[k0 * 512 + j] - Wze[k0 * 512 + j];
        float az1 = Wzh[(k0 + 1) * 512 + j] - Wze[(k0 + 1) * 512 + j];
        warz[tid] = make_uint2(pkh2(ar0, ar1), pkh2(az0, az1));
    }
    int t2 = tid - 256 * 512;
    if (t2 >= 0 && t2 < 512 * 512) {
        int k = t2 >> 9, j = t2 & 511;
        float an = Wnh[k * 512 + j] - Wne[k * 512 + j];
        wan[t2] = pkh2(an, Wne[k * 512 + j]);
    }
}

// ---------------------------------------------------------------------------
// init hbuf2: [256 kp][64 m] u64 = {pkh2(h[m][2kp], h[m][2kp+1]), tag=0}
// ---------------------------------------------------------------------------
__global__ void init_hbuf(const float* __restrict__ h0, u64* __restrict__ hbuf2) {
    int tid = blockIdx.x * blockDim.x + threadIdx.x;   // 256*64
    if (tid >= 256 * 64) return;
    int kp = tid >> 6, m = tid & 63;
    hbuf2[tid] = pack_tag(pkh2(h0[m * 512 + 2 * kp], h0[m * 512 + 2 * kp + 1]), 0u);
}

// ---------------------------------------------------------------------------
// GEMM-X: writes xproj directly in scan layout xT[t][col][m] bf16.
// ---------------------------------------------------------------------------
__global__ __launch_bounds__(256)
void gemmx_kernel(const float* __restrict__ A, const unsigned short* __restrict__ BT,
                  const float* __restrict__ bias, unsigned short* __restrict__ xT) {
    __shared__ unsigned short Asm[128 * 64];
    __shared__ unsigned short Bsm[128 * 64];
    __shared__ unsigned short Csm[128][128];   // [col][row]
    const int tid = threadIdx.x;
    const int t0 = blockIdx.x * 2;        // time-pair
    const int c0 = blockIdx.y * 128;      // col tile
    const int lane = tid & 63, wid = tid >> 6;
    const int wm = wid >> 1, wn = wid & 1;
    const int lr = lane & 15, lg = lane >> 4;

    f32x4 acc[4][4] = {};

    const int srow = tid >> 1, shalf = tid & 1;
    const int rowA = (srow & 63) * 512 + t0 + (srow >> 6);     // (b,t) -> A row
    const float* Arow = A + (size_t)rowA * 256 + shalf * 32;
    const unsigned short* Brow = BT + (size_t)(c0 + srow) * 256 + shalf * 32;
    unsigned short* As = &Asm[srow * 64 + shalf * 32];
    unsigned short* Bs = &Bsm[srow * 64 + shalf * 32];

    for (int kt = 0; kt < 256; kt += 64) {
#pragma unroll
        for (int q = 0; q < 8; q++) {
            float4 v = *(const float4*)(Arow + kt + q * 4);
            unsigned p0 = ((unsigned)f32_to_bf16(v.y) << 16) | f32_to_bf16(v.x);
            unsigned p1 = ((unsigned)f32_to_bf16(v.w) << 16) | f32_to_bf16(v.z);
            *(uint2*)(As + q * 4) = make_uint2(p0, p1);
        }
#pragma unroll
        for (int q = 0; q < 4; q++) {
            uint4 v = *(const uint4*)(Brow + kt + q * 8);
            *(uint4*)(Bs + q * 8) = v;
        }
        __syncthreads();
#pragma unroll
        for (int ks = 0; ks < 2; ks++) {
            bf16x8 af[4], bfr[4];
#pragma unroll
            for (int m = 0; m < 4; m++)
                af[m] = *(const bf16x8*)&Asm[(wm * 64 + m * 16 + lr) * 64 + ks * 32 + lg * 8];
#pragma unroll
            for (int n2 = 0; n2 < 4; n2++)
                bfr[n2] = *(const bf16x8*)&Bsm[(wn * 64 + n2 * 16 + lr) * 64 + ks * 32 + lg * 8];
#pragma unroll
            for (int m = 0; m < 4; m++)
#pragma unroll
                for (int n2 = 0; n2 < 4; n2++)
                    acc[m][n2] = __builtin_amdgcn_mfma_f32_16x16x32_bf16(
                        af[m], bfr[n2], acc[m][n2], 0, 0, 0);
        }
        __syncthreads();
    }
#pragma unroll
    for (int m = 0; m < 4; m++) {
        int r0 = wm * 64 + m * 16 + lg * 4;
#pragma unroll
        for (int n2 = 0; n2 < 4; n2++) {
            int c = wn * 64 + n2 * 16 + lr;
            float bv = bias[c0 + c];
#pragma unroll
            for (int i = 0; i < 4; i++)
                Csm[c][r0 + i] = f32_to_bf16(acc[m][n2][i] + bv);
        }
    }
    __syncthreads();
#pragma unroll
    for (int th = 0; th < 2; th++) {
        uint4* dst = (uint4*)(xT + ((size_t)(t0 + th) * 2048 + c0) * 64);
        for (int q = tid; q < 1024; q += 256) {
            int c = q >> 3, b0 = (q & 7) * 8;
            dst[q] = *(const uint4*)&Csm[c][th * 64 + b0];
        }
        __syncthreads();
    }
}

// ---------------------------------------------------------------------------
// Readout GEMM: A fp32 [M][K], BT bf16 [N][K], C fp32 + bias.
// ---------------------------------------------------------------------------
__global__ __launch_bounds__(256)
void gemm_out_kernel(const float* __restrict__ A, const unsigned short* __restrict__ BT,
                     const float* __restrict__ bias, float* __restrict__ C,
                     int M, int N, int K) {
    __shared__ unsigned short Asm[128 * 64];
    __shared__ unsigned short Bsm[128 * 64];
    const int tid = threadIdx.x;
    const int bm = blockIdx.x, bn = blockIdx.y;
    const int lane = tid & 63, wid = tid >> 6;
    const int wm = wid >> 1, wn = wid & 1;
    const int lr = lane & 15, lg = lane >> 4;

    f32x4 acc[4][4] = {};

    const int srow = tid >> 1, shalf = tid & 1;
    const float* Arow = A + (size_t)(bm * 128 + srow) * K + shalf * 32;
    const unsigned short* Brow = BT + (size_t)(bn * 128 + srow) * K + shalf * 32;
    unsigned short* As = &Asm[srow * 64 + shalf * 32];
    unsigned short* Bs = &Bsm[srow * 64 + shalf * 32];

    for (int kt = 0; kt < K; kt += 64) {
#pragma unroll
        for (int q = 0; q < 8; q++) {
            float4 v = *(const float4*)(Arow + kt + q * 4);
            unsigned p0 = ((unsigned)f32_to_bf16(v.y) << 16) | f32_to_bf16(v.x);
            unsigned p1 = ((unsigned)f32_to_bf16(v.w) << 16) | f32_to_bf16(v.z);
            *(uint2*)(As + q * 4) = make_uint2(p0, p1);
        }
#pragma unroll
        for (int q = 0; q < 4; q++) {
            uint4 v = *(const uint4*)(Brow + kt + q * 8);
            *(uint4*)(Bs + q * 8) = v;
        }
        __syncthreads();
#pragma unroll
        for (int ks = 0; ks < 2; ks++) {
            bf16x8 af[4], bfr[4];
#pragma unroll
            for (int m = 0; m < 4; m++)
                af[m] = *(const bf16x8*)&Asm[(wm * 64 + m * 16 + lr) * 64 + ks * 32 + lg * 8];
#pragma unroll
            for (int n2 = 0; n2 < 4; n2++)
                bfr[n2] = *(const bf16x8*)&Bsm[(wn * 64 + n2 * 16 + lr) * 64 + ks * 32 + lg * 8];
#pragma unroll
            for (int m = 0; m < 4; m++)
#pragma unroll
                for (int n2 = 0; n2 < 4; n2++)
                    acc[m][n2] = __builtin_amdgcn_mfma_f32_16x16x32_bf16(
                        af[m], bfr[n2], acc[m][n2], 0, 0, 0);
        }
        __syncthreads();
    }
#pragma unroll
    for (int m = 0; m < 4; m++) {
        int row0 = bm * 128 + wm * 64 + m * 16 + lg * 4;
#pragma unroll
        for (int n2 = 0; n2 < 4; n2++) {
            int col = bn * 128 + wn * 64 + n2 * 16 + lr;
            float bv = bias[col];
#pragma unroll
            for (int i = 0; i < 4; i++)
                C[(size_t)(row0 + i) * N + col] = acc[m][n2][i] + bv;
        }
    }
}

// ---------------------------------------------------------------------------
// Grid-synced weight-stationary scan, self-tagged exchange (round-12 scheme)
// with DISCIPLINED polling:
//  1) sentinel pre-gate: lanes 0-7 poll ONE element per producer block
//     (8 loads/wave/iter, tight loop) -- fast observe, tiny traffic.
//  2) bulk load + per-element tag verify; stragglers re-read only after
//     s_sleep(8) (~210ns). Correctness rests on (2); (1) is heuristic.
// Tag lattice correctness proven in round 12 (deterministic 0.015625).
// hbuf rows [bid*4..+4) per block; wave wv reads kp [32wv..+32) from
// producers 8wv..8wv+7 (sentinel row 32wv+4i+3). rhrxe rows [bid*8..+8);
// wave wv reads k [64wv..+64) (sentinel row 64wv+8i+7).
// ---------------------------------------------------------------------------
__global__ __launch_bounds__(512)
void scan_sync(const unsigned short* __restrict__ xT,   // [512 t][2048 col][64 m] bf16
               const float* __restrict__ h0,            // [64 m][512 j]
               const uint2* __restrict__ warz,          // [256 kp][512 j]
               const uint* __restrict__ wan,            // [512 k][512 j]
               u64* __restrict__ hbuf2,                 // [256 kp][64 m] tagged
               u64* __restrict__ rhrxe2,                // [512 k][64 m] tagged
               float* __restrict__ hseq)                // [64 m][512 t][512 j]
{
    __shared__ uint2 Wrz_l[256][JO];                    // 16 KB
    __shared__ uint  Wn_l[512][JO];                     // 16 KB
    __shared__ float part[3][8][JO][64];                // 48 KB
    __shared__ float h_loc[JO][64], z_loc[JO][64];      // 4 KB

    const int bid = blockIdx.x, tid = threadIdx.x;
    const int lane = tid & 63, wv = tid >> 6;           // 8 waves
    const int j0 = bid * JO;
    const int jF = tid >> 6, mF = tid & 63;             // finalize mapping

    // one-time: weights -> LDS, local h slice
    for (int i = tid; i < 256 * JO; i += 512) {
        int kp = i >> 3, j = i & 7;
        Wrz_l[kp][j] = warz[kp * 512 + j0 + j];
    }
    for (int i = tid; i < 512 * JO; i += 512) {
        int k = i >> 3, j = i & 7;
        Wn_l[k][j] = wan[k * 512 + j0 + j];
    }
    h_loc[jF][mF] = h0[mF * 512 + j0 + jF];
    __syncthreads();

    const int jg = j0 + jF;
    const size_t xoff = (size_t)jg * 64 + mF;
    const bool sl = (lane < 8);                         // sentinel lanes
    const u64* sH = sl ? &hbuf2[(wv * 32 + 4 * lane + 3) * 64 + lane] : (const u64*)0;
    const u64* sR = sl ? &rhrxe2[(wv * 64 + 8 * lane + 7) * 64 + lane] : (const u64*)0;

    for (int t = 0; t < T_; t++) {
        const uint tagH = (uint)t;          // hbuf freshness for this step
        const uint tagR = (uint)t + 1u;     // rhrxe freshness for this step

        // xT gate loads: issued early, latency hides under the hbuf poll
        const size_t xb = (size_t)t * 2048 * 64 + xoff;
        unsigned short pxe = xT[xb];
        unsigned short pxr = xT[xb + (size_t)512 * 64];
        unsigned short pxz = xT[xb + (size_t)1024 * 64];
        unsigned short pxn = xT[xb + (size_t)1536 * 64];

        // ---- phase A: gated poll-load of hbuf rows (kp = wv*32..+32) ----
        {
            // sentinel gate
            {
                int it = 0;
                while (true) {
                    uint tg = sl ? (uint)(ald64(sH) >> 32) : tagH;
                    if (__all(tg == tagH) || ++it > (1 << 22)) break;
                }
            }
            u64 raw[32];
#pragma unroll
            for (int q = 0; q < 32; q++)
                raw[q] = ald64(&hbuf2[(wv * 32 + q) * 64 + lane]);
            int it = 0;
            while (true) {
                uint stale = 0;
#pragma unroll
                for (int q = 0; q < 32; q++)
                    stale |= ((uint)(raw[q] >> 32) != tagH) ? 1u : 0u;
                if (!__any(stale) || ++it > (1 << 18)) break;
                __builtin_amdgcn_s_sleep(8);           // ~210ns throttle
#pragma unroll
                for (int q = 0; q < 32; q++)
                    if ((uint)(raw[q] >> 32) != tagH)
                        raw[q] = ald64(&hbuf2[(wv * 32 + q) * 64 + lane]);
            }
            float ar[JO] = {}, az[JO] = {};
#pragma unroll
            for (int q = 0; q < 32; q++) {
                half2_t h2 = uph2((uint)raw[q]);
#pragma unroll
                for (int j = 0; j < JO; j++) {
                    uint2 w = *(const uint2*)&Wrz_l[wv * 32 + q][j];
                    ar[j] = fdot2(h2, uph2(w.x), ar[j]);
                    az[j] = fdot2(h2, uph2(w.y), az[j]);
                }
            }
#pragma unroll
            for (int j = 0; j < JO; j++) {
                part[0][wv][j][lane] = ar[j];
                part[1][wv][j][lane] = az[j];
            }
        }
        __syncthreads();

        // ---- finalize A: sigmoid, publish tagged (r*h, r*xe) ----
        float xn_f = bf16_to_f32(pxn);
        {
            float sr = 0.f, sz = 0.f;
#pragma unroll
            for (int w = 0; w < 8; w++) { sr += part[0][w][jF][mF]; sz += part[1][w][jF][mF]; }
            float r = sigmoidf_(bf16_to_f32(pxr) + sr);
            float z = sigmoidf_(bf16_to_f32(pxz) + sz);
            float h = h_loc[jF][mF];
            z_loc[jF][mF] = z;
            ast64(&rhrxe2[jg * 64 + mF],
                  pack_tag(pkh2(r * h, r * bf16_to_f32(pxe)), tagR));
        }
        // no barrier, no drain: rhrxe elements are self-tagged

        // ---- phase B: gated poll-load of rhrxe rows (k = wv*64..+64) ----
        {
            // sentinel gate (covers both chunks)
            {
                int it = 0;
                while (true) {
                    uint tg = sl ? (uint)(ald64(sR) >> 32) : tagR;
                    if (__all(tg == tagR) || ++it > (1 << 22)) break;
                }
            }
            float an[JO] = {};
#pragma unroll
            for (int ch = 0; ch < 2; ch++) {
                u64 raw[32];
#pragma unroll
                for (int q = 0; q < 32; q++)
                    raw[q] = ald64(&rhrxe2[(wv * 64 + ch * 32 + q) * 64 + lane]);
                int it = 0;
                while (true) {
                    uint stale = 0;
#pragma unroll
                    for (int q = 0; q < 32; q++)
                        stale |= ((uint)(raw[q] >> 32) != tagR) ? 1u : 0u;
                    if (!__any(stale) || ++it > (1 << 18)) break;
                    __builtin_amdgcn_s_sleep(8);
#pragma unroll
                    for (int q = 0; q < 32; q++)
                        if ((uint)(raw[q] >> 32) != tagR)
                            raw[q] = ald64(&rhrxe2[(wv * 64 + ch * 32 + q) * 64 + lane]);
                }
#pragma unroll
                for (int q = 0; q < 32; q++) {
                    half2_t p2 = uph2((uint)raw[q]);
#pragma unroll
                    for (int j = 0; j < JO; j++)
                        an[j] = fdot2(p2, uph2(Wn_l[wv * 64 + ch * 32 + q][j]), an[j]);
                }
            }
#pragma unroll
            for (int j = 0; j < JO; j++) part[2][wv][j][lane] = an[j];
        }
        __syncthreads();

        // ---- finalize B: tanh, h update ----
        {
            float sn = 0.f;
#pragma unroll
            for (int w = 0; w < 8; w++) sn += part[2][w][jF][mF];
            float nn = tanhf(xn_f + sn);
            float z = z_loc[jF][mF];
            float h = h_loc[jF][mF];
            h_loc[jF][mF] = (1.f - z) * h + z * nn;
        }
        __syncthreads();

        // ---- publish new h (tagged f16 pairs) ----
        if (tid < (JO / 2) * 64) {
            int jp = tid >> 6, mh = tid & 63;
            ast64(&hbuf2[(bid * (JO / 2) + jp) * 64 + mh],
                  pack_tag(pkh2(h_loc[2 * jp][mh], h_loc[2 * jp + 1][mh]),
                           (uint)t + 1u));
        }
        // ---- hseq write: off the critical path ----
        {
            int js = tid & 7, ms = tid >> 3;
            hseq[((size_t)ms * 512 + t) * 512 + j0 + js] = h_loc[js][ms];
        }
    }
}

// ---------------------------------------------------------------------------
extern "C" void kernel_launch(void* const* d_in, const int* in_sizes, int n_in,
                              void* d_out, int out_size, void* d_ws, size_t ws_size,
                              hipStream_t stream) {
    const float* x    = (const float*)d_in[0];
    const float* h0   = (const float*)d_in[1];
    const float* We2h = (const float*)d_in[2];
    const float* Wrx  = (const float*)d_in[3];
    const float* Wrh  = (const float*)d_in[4];
    const float* Wre  = (const float*)d_in[5];
    const float* br   = (const float*)d_in[6];
    const float* Wzx  = (const float*)d_in[7];
    const float* Wzh  = (const float*)d_in[8];
    const float* Wze  = (const float*)d_in[9];
    const float* bz   = (const float*)d_in[10];
    const float* Wnx  = (const float*)d_in[11];
    const float* Wnh  = (const float*)d_in[12];
    const float* Wne  = (const float*)d_in[13];
    const float* bn   = (const float*)d_in[14];
    const float* Wo   = (const float*)d_in[15];
    const float* bo   = (const float*)d_in[16];

    // workspace layout (bytes)
    char* w = (char*)d_ws;
    unsigned short* xT    = (unsigned short*)(w);                  // 134217728
    uint2*          warz  = (uint2*)(w + 134217728);               // 1048576
    uint*           wan   = (uint*)(w + 135266304);                // 1048576
    unsigned short* WcatT = (unsigned short*)(w + 136314880);      // 1048576
    unsigned short* WoT   = (unsigned short*)(w + 137363456);      // 262144
    float*          biascat = (float*)(w + 137625600);             // 8192
    float*          Pr    = (float*)(w + 137633792);               // 524288
    float*          Pz    = (float*)(w + 138158080);               // 524288
    u64*            hbuf2 = (u64*)(w + 138682368);                 // 131072
    u64*            rhrxe2= (u64*)(w + 138813440);                 // 262144

    float* out  = (float*)d_out;                    // [B,T,D]
    float* hseq = (float*)d_out + (size_t)M_ * D_;  // [B,T,H]

    // zero rhrxe tags each launch (stale cross-call tags must never match)
    hipMemsetAsync(rhrxe2, 0, 262144, stream);

    // 1. composite input weights + packed scan weights
    comp_p<<<(256 * 512 + 255) / 256, 256, 0, stream>>>(We2h, Wre, Wze, Pr, Pz);
    build_wt<<<(2048 * 256 + 256 * 512 + 255) / 256, 256, 0, stream>>>(
        We2h, Wrx, Wzx, Wnx, Pr, Pz, br, bz, bn, Wo, WcatT, biascat, WoT);
    build_wscan<<<(256 * 512 + 512 * 512 + 255) / 256, 256, 0, stream>>>(
        Wrh, Wre, Wzh, Wze, Wnh, Wne, warz, wan);
    init_hbuf<<<(256 * 64 + 255) / 256, 256, 0, stream>>>(h0, hbuf2);

    // 2. pre-projections directly into xT[t][col][m]
    {
        dim3 grid(T_ / 2, 2048 / 128);
        gemmx_kernel<<<grid, 256, 0, stream>>>(x, WcatT, biascat, xT);
    }
    // 3. scan with self-tagged exchanges -> hseq
    scan_sync<<<NBLK, 512, 0, stream>>>(xT, h0, warz, wan, hbuf2, rhrxe2, hseq);
    // 4. readout: [32768,512] @ [512,256] + bo -> out
    {
        dim3 grid(M_ / 128, D_ / 128);
        gemm_out_kernel<<<grid, 256, 0, stream>>>(hseq, WoT, bo, out, M_, D_, H_);
    }
}

// Round 14
// 5338.678 us; speedup vs baseline: 4.4354x; 4.3972x over previous
//
#include <hip/hip_runtime.h>
#include <hip/hip_bf16.h>
#include <hip/hip_fp16.h>

// Problem constants
#define B_ 64
#define T_ 512
#define D_ 256
#define H_ 512
#define M_ (B_*T_)          // 32768

#define NBLK 64             // scan blocks
#define JO 8                // hidden columns owned per scan block

typedef unsigned int uint;
typedef __attribute__((ext_vector_type(8))) short bf16x8;
typedef __attribute__((ext_vector_type(4))) float f32x4;
typedef _Float16 half_t;
typedef __attribute__((ext_vector_type(2))) _Float16 half2_t;

__device__ __forceinline__ unsigned short f32_to_bf16(float f) {
    unsigned u = __builtin_bit_cast(unsigned, f);
    unsigned r = (u + 0x7fffu + ((u >> 16) & 1u)) >> 16;
    return (unsigned short)r;
}
__device__ __forceinline__ float bf16_to_f32(unsigned short h) {
    unsigned u = ((unsigned)h) << 16;
    return __builtin_bit_cast(float, u);
}
__device__ __forceinline__ unsigned pkh2(float a, float b) {
    half2_t h; h.x = (half_t)a; h.y = (half_t)b;
    return __builtin_bit_cast(unsigned, h);
}
__device__ __forceinline__ half2_t uph2(unsigned u) {
    return __builtin_bit_cast(half2_t, u);
}

#if __has_builtin(__builtin_amdgcn_fdot2)
__device__ __forceinline__ float fdot2(half2_t a, half2_t b, float c) {
    return __builtin_amdgcn_fdot2(a, b, c, false);
}
#else
__device__ __forceinline__ float fdot2(half2_t a, half2_t b, float c) {
    return c + (float)a.x * (float)b.x + (float)a.y * (float)b.y;
}
#endif

// agent-scope (cross-XCD coherent) relaxed 32-bit atomics.
// NOTE (r12/r13 lesson): 32-bit agent atomics are cache-served (~470MB total
// exchange traffic); 64-bit agent atomics go uncached to HBM (19GB, 4x slower).
__device__ __forceinline__ uint ald(const uint* p) {
    return __hip_atomic_load(p, __ATOMIC_RELAXED, __HIP_MEMORY_SCOPE_AGENT);
}
__device__ __forceinline__ void ast(uint* p, uint v) {
    __hip_atomic_store(p, v, __ATOMIC_RELAXED, __HIP_MEMORY_SCOPE_AGENT);
}

__device__ __forceinline__ float sigmoidf_(float x) {
    return 1.f / (1.f + __expf(-x));
}

// Single-hop flag-array grid barrier (round-8 proven structure).
//  arrival: block bid stores monotonic `target` into flags[bid*4] (no RMW).
//  detect:  wave 0 of EVERY block polls all 64 flags (lane l -> flags[l*4]),
//           exits on __all(f >= target). One L3 hop.
//  entry __syncthreads drains this block's publish stores (vmcnt(0) before
//  s_barrier); exit is a RAW s_barrier so other waves' in-flight ops survive.
__device__ __forceinline__ void gbar(uint* flags, uint target, int tid, int bid) {
    __syncthreads();                      // drain publishes; all waves synced
    if (tid < 64) {                       // wave 0
        if (tid == 0)
            ast(&flags[bid * 4], target);
        int it = 0;
        uint f;
        do {
            f = ald(&flags[tid * 4]);
            if (++it > (1 << 24)) break;  // bounded: fail loud, not hang
        } while (!__all(f >= target));
    }
    __builtin_amdgcn_s_barrier();         // raw: no vmcnt drain on exit
}

// ---------------------------------------------------------------------------
// P = We2h @ W  for r and z gates
// ---------------------------------------------------------------------------
__global__ void comp_p(const float* __restrict__ We2h, const float* __restrict__ Wre,
                       const float* __restrict__ Wze,
                       float* __restrict__ Pr, float* __restrict__ Pz) {
    int tid = blockIdx.x * blockDim.x + threadIdx.x;   // 256*512
    if (tid >= 256 * 512) return;
    int k = tid >> 9, j = tid & 511;
    float ar = 0.f, az = 0.f;
    for (int kk = 0; kk < 512; kk++) {
        float e = We2h[k * 512 + kk];
        ar += e * Wre[kk * 512 + j];
        az += e * Wze[kk * 512 + j];
    }
    Pr[tid] = ar;
    Pz[tid] = az;
}

// ---------------------------------------------------------------------------
// Build bf16 weights for the big GEMMs.
// ---------------------------------------------------------------------------
__global__ void build_wt(const float* __restrict__ We2h, const float* __restrict__ Wrx,
                         const float* __restrict__ Wzx, const float* __restrict__ Wnx,
                         const float* __restrict__ Pr, const float* __restrict__ Pz,
                         const float* __restrict__ br, const float* __restrict__ bz,
                         const float* __restrict__ bn, const float* __restrict__ Wo,
                         unsigned short* __restrict__ WcatT, float* __restrict__ biascat,
                         unsigned short* __restrict__ WoT) {
    int tid = blockIdx.x * blockDim.x + threadIdx.x;
    const int total1 = 2048 * 256;
    if (tid < total1) {
        int n = tid >> 8, k = tid & 255;
        int sel = n >> 9, nl = n & 511;
        float v;
        if (sel == 0)      v = We2h[k * 512 + nl];
        else if (sel == 1) v = Wrx[k * 512 + nl] + Pr[k * 512 + nl];
        else if (sel == 2) v = Wzx[k * 512 + nl] + Pz[k * 512 + nl];
        else               v = Wnx[k * 512 + nl];
        WcatT[tid] = f32_to_bf16(v);
        if (k == 0) {
            float bv = sel == 0 ? 0.f : sel == 1 ? br[nl] : sel == 2 ? bz[nl] : bn[nl];
            biascat[n] = bv;
        }
    } else {
        int t2 = tid - total1;
        if (t2 < 256 * 512) {
            int n = t2 >> 9, k = t2 & 511;
            WoT[t2] = f32_to_bf16(Wo[k * 256 + n]);
        }
    }
}

// ---------------------------------------------------------------------------
// Packed f16 recurrent weights (transformed):
//  warz uint2 [256 kp][512 j]: {pkh2(Ar[2kp],Ar[2kp+1]), pkh2(Az...)}, A=Wh-We
//  wan  uint  [512 k][512 j]:  pkh2(An[k][j], Wne[k][j]),  An = Wnh - Wne
// ---------------------------------------------------------------------------
__global__ void build_wscan(const float* __restrict__ Wrh, const float* __restrict__ Wre,
                            const float* __restrict__ Wzh, const float* __restrict__ Wze,
                            const float* __restrict__ Wnh, const float* __restrict__ Wne,
                            uint2* __restrict__ warz, uint* __restrict__ wan) {
    int tid = blockIdx.x * blockDim.x + threadIdx.x;
    if (tid < 256 * 512) {
        int kp = tid >> 9, j = tid & 511;
        int k0 = 2 * kp;
        float ar0 = Wrh[k0 * 512 + j] - Wre[k0 * 512 + j];
        float ar1 = Wrh[(k0 + 1) * 512 + j] - Wre[(k0 + 1) * 512 + j];
        float az0 = Wzh[k0 * 512 + j] - Wze[k0 * 512 + j];
        float az1 = Wzh[(k0 + 1) * 512 + j] - Wze[(k0 + 1) * 512 + j];
        warz[tid] = make_uint2(pkh2(ar0, ar1), pkh2(az0, az1));
    }
    int t2 = tid - 256 * 512;
    if (t2 >= 0 && t2 < 512 * 512) {
        int k = t2 >> 9, j = t2 & 511;
        float an = Wnh[k * 512 + j] - Wne[k * 512 + j];
        wan[t2] = pkh2(an, Wne[k * 512 + j]);
    }
}

// ---------------------------------------------------------------------------
// init hbuf: [256 kp][64 m] uint = (f16 h[m][2kp], f16 h[m][2kp+1])
// ---------------------------------------------------------------------------
__global__ void init_hbuf(const float* __restrict__ h0, uint* __restrict__ hbuf) {
    int tid = blockIdx.x * blockDim.x + threadIdx.x;   // 256*64
    if (tid >= 256 * 64) return;
    int kp = tid >> 6, m = tid & 63;
    hbuf[tid] = pkh2(h0[m * 512 + 2 * kp], h0[m * 512 + 2 * kp + 1]);
}

// ---------------------------------------------------------------------------
// GEMM-X: writes xproj directly in scan layout xT[t][col][m] bf16.
// ---------------------------------------------------------------------------
__global__ __launch_bounds__(256)
void gemmx_kernel(const float* __restrict__ A, const unsigned short* __restrict__ BT,
                  const float* __restrict__ bias, unsigned short* __restrict__ xT) {
    __shared__ unsigned short Asm[128 * 64];
    __shared__ unsigned short Bsm[128 * 64];
    __shared__ unsigned short Csm[128][128];   // [col][row]
    const int tid = threadIdx.x;
    const int t0 = blockIdx.x * 2;        // time-pair
    const int c0 = blockIdx.y * 128;      // col tile
    const int lane = tid & 63, wid = tid >> 6;
    const int wm = wid >> 1, wn = wid & 1;
    const int lr = lane & 15, lg = lane >> 4;

    f32x4 acc[4][4] = {};

    const int srow = tid >> 1, shalf = tid & 1;
    const int rowA = (srow & 63) * 512 + t0 + (srow >> 6);     // (b,t) -> A row
    const float* Arow = A + (size_t)rowA * 256 + shalf * 32;
    const unsigned short* Brow = BT + (size_t)(c0 + srow) * 256 + shalf * 32;
    unsigned short* As = &Asm[srow * 64 + shalf * 32];
    unsigned short* Bs = &Bsm[srow * 64 + shalf * 32];

    for (int kt = 0; kt < 256; kt += 64) {
#pragma unroll
        for (int q = 0; q < 8; q++) {
            float4 v = *(const float4*)(Arow + kt + q * 4);
            unsigned p0 = ((unsigned)f32_to_bf16(v.y) << 16) | f32_to_bf16(v.x);
            unsigned p1 = ((unsigned)f32_to_bf16(v.w) << 16) | f32_to_bf16(v.z);
            *(uint2*)(As + q * 4) = make_uint2(p0, p1);
        }
#pragma unroll
        for (int q = 0; q < 4; q++) {
            uint4 v = *(const uint4*)(Brow + kt + q * 8);
            *(uint4*)(Bs + q * 8) = v;
        }
        __syncthreads();
#pragma unroll
        for (int ks = 0; ks < 2; ks++) {
            bf16x8 af[4], bfr[4];
#pragma unroll
            for (int m = 0; m < 4; m++)
                af[m] = *(const bf16x8*)&Asm[(wm * 64 + m * 16 + lr) * 64 + ks * 32 + lg * 8];
#pragma unroll
            for (int n2 = 0; n2 < 4; n2++)
                bfr[n2] = *(const bf16x8*)&Bsm[(wn * 64 + n2 * 16 + lr) * 64 + ks * 32 + lg * 8];
#pragma unroll
            for (int m = 0; m < 4; m++)
#pragma unroll
                for (int n2 = 0; n2 < 4; n2++)
                    acc[m][n2] = __builtin_amdgcn_mfma_f32_16x16x32_bf16(
                        af[m], bfr[n2], acc[m][n2], 0, 0, 0);
        }
        __syncthreads();
    }
#pragma unroll
    for (int m = 0; m < 4; m++) {
        int r0 = wm * 64 + m * 16 + lg * 4;
#pragma unroll
        for (int n2 = 0; n2 < 4; n2++) {
            int c = wn * 64 + n2 * 16 + lr;
            float bv = bias[c0 + c];
#pragma unroll
            for (int i = 0; i < 4; i++)
                Csm[c][r0 + i] = f32_to_bf16(acc[m][n2][i] + bv);
        }
    }
    __syncthreads();
#pragma unroll
    for (int th = 0; th < 2; th++) {
        uint4* dst = (uint4*)(xT + ((size_t)(t0 + th) * 2048 + c0) * 64);
        for (int q = tid; q < 1024; q += 256) {
            int c = q >> 3, b0 = (q & 7) * 8;
            dst[q] = *(const uint4*)&Csm[c][th * 64 + b0];
        }
        __syncthreads();
    }
}

// ---------------------------------------------------------------------------
// Readout GEMM: A fp32 [M][K], BT bf16 [N][K], C fp32 + bias.
// ---------------------------------------------------------------------------
__global__ __launch_bounds__(256)
void gemm_out_kernel(const float* __restrict__ A, const unsigned short* __restrict__ BT,
                     const float* __restrict__ bias, float* __restrict__ C,
                     int M, int N, int K) {
    __shared__ unsigned short Asm[128 * 64];
    __shared__ unsigned short Bsm[128 * 64];
    const int tid = threadIdx.x;
    const int bm = blockIdx.x, bn = blockIdx.y;
    const int lane = tid & 63, wid = tid >> 6;
    const int wm = wid >> 1, wn = wid & 1;
    const int lr = lane & 15, lg = lane >> 4;

    f32x4 acc[4][4] = {};

    const int srow = tid >> 1, shalf = tid & 1;
    const float* Arow = A + (size_t)(bm * 128 + srow) * K + shalf * 32;
    const unsigned short* Brow = BT + (size_t)(bn * 128 + srow) * K + shalf * 32;
    unsigned short* As = &Asm[srow * 64 + shalf * 32];
    unsigned short* Bs = &Bsm[srow * 64 + shalf * 32];

    for (int kt = 0; kt < K; kt += 64) {
#pragma unroll
        for (int q = 0; q < 8; q++) {
            float4 v = *(const float4*)(Arow + kt + q * 4);
            unsigned p0 = ((unsigned)f32_to_bf16(v.y) << 16) | f32_to_bf16(v.x);
            unsigned p1 = ((unsigned)f32_to_bf16(v.w) << 16) | f32_to_bf16(v.z);
            *(uint2*)(As + q * 4) = make_uint2(p0, p1);
        }
#pragma unroll
        for (int q = 0; q < 4; q++) {
            uint4 v = *(const uint4*)(Brow + kt + q * 8);
            *(uint4*)(Bs + q * 8) = v;
        }
        __syncthreads();
#pragma unroll
        for (int ks = 0; ks < 2; ks++) {
            bf16x8 af[4], bfr[4];
#pragma unroll
            for (int m = 0; m < 4; m++)
                af[m] = *(const bf16x8*)&Asm[(wm * 64 + m * 16 + lr) * 64 + ks * 32 + lg * 8];
#pragma unroll
            for (int n2 = 0; n2 < 4; n2++)
                bfr[n2] = *(const bf16x8*)&Bsm[(wn * 64 + n2 * 16 + lr) * 64 + ks * 32 + lg * 8];
#pragma unroll
            for (int m = 0; m < 4; m++)
#pragma unroll
                for (int n2 = 0; n2 < 4; n2++)
                    acc[m][n2] = __builtin_amdgcn_mfma_f32_16x16x32_bf16(
                        af[m], bfr[n2], acc[m][n2], 0, 0, 0);
        }
        __syncthreads();
    }
#pragma unroll
    for (int m = 0; m < 4; m++) {
        int row0 = bm * 128 + wm * 64 + m * 16 + lg * 4;
#pragma unroll
        for (int n2 = 0; n2 < 4; n2++) {
            int col = bn * 128 + wn * 64 + n2 * 16 + lr;
            float bv = bias[col];
#pragma unroll
            for (int i = 0; i < 4; i++)
                C[(size_t)(row0 + i) * N + col] = acc[m][n2][i] + bv;
        }
    }
}

// ---------------------------------------------------------------------------
// Grid-synced weight-stationary scan (round-8 proven structure) with one
// overlap improvement: in barrier 2, the flagH store goes out immediately
// after the drain, and the hseq store + next-step xT prefetch are issued
// DURING the poll window (they fly across the raw exit s_barrier).
// ---------------------------------------------------------------------------
__global__ __launch_bounds__(512)
void scan_sync(const unsigned short* __restrict__ xT,   // [512 t][2048 col][64 m] bf16
               const float* __restrict__ h0,            // [64 m][512 j]
               const uint2* __restrict__ warz,          // [256 kp][512 j]
               const uint* __restrict__ wan,            // [512 k][512 j]
               uint* __restrict__ hbuf,                 // [256 kp][64 m]
               uint* __restrict__ rhrxe,                // [512 k][64 m]
               uint* __restrict__ flags,                // [NBLK*4]
               float* __restrict__ hseq)                // [64 m][512 t][512 j]
{
    __shared__ uint2 Wrz_l[256][JO];                    // 16 KB
    __shared__ uint  Wn_l[512][JO];                     // 16 KB
    __shared__ float part[3][8][JO][64];                // 48 KB
    __shared__ float h_loc[JO][64], z_loc[JO][64];      // 4 KB

    const int bid = blockIdx.x, tid = threadIdx.x;
    const int lane = tid & 63, wv = tid >> 6;           // 8 waves
    const int j0 = bid * JO;
    const int jF = tid >> 6, mF = tid & 63;             // finalize mapping

    // one-time: weights -> LDS, local h slice
    for (int i = tid; i < 256 * JO; i += 512) {
        int kp = i >> 3, j = i & 7;
        Wrz_l[kp][j] = warz[kp * 512 + j0 + j];
    }
    for (int i = tid; i < 512 * JO; i += 512) {
        int k = i >> 3, j = i & 7;
        Wn_l[k][j] = wan[k * 512 + j0 + j];
    }
    h_loc[jF][mF] = h0[mF * 512 + j0 + jF];
    __syncthreads();

    // xT gate loads for step 0 (raw ushorts; convert at use)
    const int jg = j0 + jF;
    const size_t xoff = (size_t)jg * 64 + mF;
    unsigned short pxe = xT[xoff];
    unsigned short pxr = xT[xoff + (size_t)512 * 64];
    unsigned short pxz = xT[xoff + (size_t)1024 * 64];
    unsigned short pxn = xT[xoff + (size_t)1536 * 64];

    for (int t = 0; t < T_; t++) {
        // ---- phase A: r,z partial dots (wave wv covers kp = wv*32..+32) ----
        {
            uint hv[32];
#pragma unroll
            for (int q = 0; q < 32; q++)
                hv[q] = ald(&hbuf[(wv * 32 + q) * 64 + lane]);
            float ar[JO] = {}, az[JO] = {};
#pragma unroll
            for (int q = 0; q < 32; q++) {
                half2_t h2 = uph2(hv[q]);
#pragma unroll
                for (int j = 0; j < JO; j++) {
                    uint2 w = *(const uint2*)&Wrz_l[wv * 32 + q][j];
                    ar[j] = fdot2(h2, uph2(w.x), ar[j]);
                    az[j] = fdot2(h2, uph2(w.y), az[j]);
                }
            }
#pragma unroll
            for (int j = 0; j < JO; j++) {
                part[0][wv][j][lane] = ar[j];
                part[1][wv][j][lane] = az[j];
            }
        }
        __syncthreads();

        // ---- finalize A (all 512 threads; coalesced rhrxe publish) ----
        float xe = bf16_to_f32(pxe), xn_f = bf16_to_f32(pxn);
        {
            float sr = 0.f, sz = 0.f;
#pragma unroll
            for (int w = 0; w < 8; w++) { sr += part[0][w][jF][mF]; sz += part[1][w][jF][mF]; }
            float r = sigmoidf_(bf16_to_f32(pxr) + sr);
            float z = sigmoidf_(bf16_to_f32(pxz) + sz);
            float h = h_loc[jF][mF];
            z_loc[jF][mF] = z;
            ast(&rhrxe[jg * 64 + mF], pkh2(r * h, r * xe));
        }
        // ---- barrier 1: all rhrxe published ----
        gbar(flags, 2u * (uint)t + 1u, tid, bid);

        // ---- phase B: n partial dots (wave wv covers k = wv*64..+64) ----
        {
            float an[JO] = {};
#pragma unroll
            for (int ch = 0; ch < 2; ch++) {
                uint rv[32];
#pragma unroll
                for (int q = 0; q < 32; q++)
                    rv[q] = ald(&rhrxe[(wv * 64 + ch * 32 + q) * 64 + lane]);
#pragma unroll
                for (int q = 0; q < 32; q++) {
                    half2_t p2 = uph2(rv[q]);
#pragma unroll
                    for (int j = 0; j < JO; j++)
                        an[j] = fdot2(p2, uph2(Wn_l[wv * 64 + ch * 32 + q][j]), an[j]);
                }
            }
#pragma unroll
            for (int j = 0; j < JO; j++) part[2][wv][j][lane] = an[j];
        }
        __syncthreads();

        // ---- finalize B: tanh, h update ----
        {
            float sn = 0.f;
#pragma unroll
            for (int w = 0; w < 8; w++) sn += part[2][w][jF][mF];
            float nn = tanhf(xn_f + sn);
            float z = z_loc[jF][mF];
            float h = h_loc[jF][mF];
            h_loc[jF][mF] = (1.f - z) * h + z * nn;
        }
        __syncthreads();

        // ---- publish new h (f16 pairs) ----
        if (tid < (JO / 2) * 64) {
            int jp = tid >> 6, mh = tid & 63;
            ast(&hbuf[(bid * (JO / 2) + jp) * 64 + mh],
                pkh2(h_loc[2 * jp][mh], h_loc[2 * jp + 1][mh]));
        }

        // ---- barrier 2 (inlined, overlap-optimized) ----
        __syncthreads();                  // drains h publishes (vmcnt(0))
        if (tid == 0)                     // announce ASAP
            ast(&flags[bid * 4], 2u * (uint)t + 2u);
        // overlap region: hseq store + next-step xT prefetch fly during the
        // poll and across the raw exit s_barrier (no drain on exit).
        {
            int js = tid & 7, ms = tid >> 3;
            hseq[((size_t)ms * 512 + t) * 512 + j0 + js] = h_loc[js][ms];
        }
        unsigned short nxe = 0, nxr = 0, nxz = 0, nxn = 0;
        if (t + 1 < T_) {
            const size_t xb = (size_t)(t + 1) * 2048 * 64 + xoff;
            nxe = xT[xb];
            nxr = xT[xb + (size_t)512 * 64];
            nxz = xT[xb + (size_t)1024 * 64];
            nxn = xT[xb + (size_t)1536 * 64];
        }
        __builtin_amdgcn_sched_barrier(0);   // pin issue before the poll
        if (tid < 64) {
            int it = 0;
            uint f;
            do {
                f = ald(&flags[tid * 4]);
                if (++it > (1 << 24)) break;
            } while (!__all(f >= 2u * (uint)t + 2u));
        }
        __builtin_amdgcn_s_barrier();
        pxe = nxe; pxr = nxr; pxz = nxz; pxn = nxn;
    }
}

// ---------------------------------------------------------------------------
extern "C" void kernel_launch(void* const* d_in, const int* in_sizes, int n_in,
                              void* d_out, int out_size, void* d_ws, size_t ws_size,
                              hipStream_t stream) {
    const float* x    = (const float*)d_in[0];
    const float* h0   = (const float*)d_in[1];
    const float* We2h = (const float*)d_in[2];
    const float* Wrx  = (const float*)d_in[3];
    const float* Wrh  = (const float*)d_in[4];
    const float* Wre  = (const float*)d_in[5];
    const float* br   = (const float*)d_in[6];
    const float* Wzx  = (const float*)d_in[7];
    const float* Wzh  = (const float*)d_in[8];
    const float* Wze  = (const float*)d_in[9];
    const float* bz   = (const float*)d_in[10];
    const float* Wnx  = (const float*)d_in[11];
    const float* Wnh  = (const float*)d_in[12];
    const float* Wne  = (const float*)d_in[13];
    const float* bn   = (const float*)d_in[14];
    const float* Wo   = (const float*)d_in[15];
    const float* bo   = (const float*)d_in[16];

    // workspace layout (bytes)
    char* w = (char*)d_ws;
    unsigned short* xT    = (unsigned short*)(w);                  // 134217728
    uint2*          warz  = (uint2*)(w + 134217728);               // 1048576
    uint*           wan   = (uint*)(w + 135266304);                // 1048576
    unsigned short* WcatT = (unsigned short*)(w + 136314880);      // 1048576
    unsigned short* WoT   = (unsigned short*)(w + 137363456);      // 262144
    float*          biascat = (float*)(w + 137625600);             // 8192
    float*          Pr    = (float*)(w + 137633792);               // 524288
    float*          Pz    = (float*)(w + 138158080);               // 524288
    uint*           hbuf  = (uint*)(w + 138682368);                // 65536
    uint*           rhrxe = (uint*)(w + 138747904);                // 131072
    uint*           flags = (uint*)(w + 138878976);                // 1024

    float* out  = (float*)d_out;                    // [B,T,D]
    float* hseq = (float*)d_out + (size_t)M_ * D_;  // [B,T,H]

    hipMemsetAsync(flags, 0, NBLK * 4 * sizeof(uint), stream);

    // 1. composite input weights + packed scan weights
    comp_p<<<(256 * 512 + 255) / 256, 256, 0, stream>>>(We2h, Wre, Wze, Pr, Pz);
    build_wt<<<(2048 * 256 + 256 * 512 + 255) / 256, 256, 0, stream>>>(
        We2h, Wrx, Wzx, Wnx, Pr, Pz, br, bz, bn, Wo, WcatT, biascat, WoT);
    build_wscan<<<(256 * 512 + 512 * 512 + 255) / 256, 256, 0, stream>>>(
        Wrh, Wre, Wzh, Wze, Wnh, Wne, warz, wan);
    init_hbuf<<<(256 * 64 + 255) / 256, 256, 0, stream>>>(h0, hbuf);

    // 2. pre-projections directly into xT[t][col][m]
    {
        dim3 grid(T_ / 2, 2048 / 128);
        gemmx_kernel<<<grid, 256, 0, stream>>>(x, WcatT, biascat, xT);
    }
    // 3. grid-synced scan -> hseq
    scan_sync<<<NBLK, 512, 0, stream>>>(xT, h0, warz, wan, hbuf, rhrxe, flags, hseq);
    // 4. readout: [32768,512] @ [512,256] + bo -> out
    {
        dim3 grid(M_ / 128, D_ / 128);
        gemm_out_kernel<<<grid, 256, 0, stream>>>(hseq, WoT, bo, out, M_, D_, H_);
    }
}